// Round 1
// baseline (248.124 us; speedup 1.0000x reference)
//
#include <hip/hip_runtime.h>
#include <stdint.h>

// Problem constants
#define B_SZ 1024
#define Z_SZ 32768
#define D_SZ 128
#define NZ   32                 // z chunks (split-Z)
#define CZ   (Z_SZ / NZ)        // 1024 z per chunk
#define TZ   64                 // z per inner tile
#define ITERS (CZ / TZ)         // 16
#define TBLK 64                 // batch rows per block (4 waves x 16)
#define WROWS 16                // batch rows per wave

// LDS strides (elements). Row byte-strides must be 16B multiples for ds_read_b128.
#define SEMB_STRIDE  136        // 64 x 136 bf16 (row-major emb tile), 272B rows
#define SEMBT_STRIDE 72         // 128 x 72 bf16 (transposed emb tile), 144B rows
#define SP_STRIDE    72         // 16 x 72 bf16 per wave (P tile), 144B rows

// Workspace layout (floats)
#define WS_O   0                              // [NZ][B][D]
#define WS_M   (NZ * B_SZ * D_SZ)             // [NZ][B]
#define WS_L   (WS_M + NZ * B_SZ)
#define WS_C   (WS_L + NZ * B_SZ)

typedef short bf16x8 __attribute__((ext_vector_type(8)));
typedef float f32x4  __attribute__((ext_vector_type(4)));

__device__ __forceinline__ unsigned short f2bf(float f) {
    union { float f; uint32_t u; } v; v.f = f;
    uint32_t u = v.u;
    u = (u + 0x7FFFu + ((u >> 16) & 1u)) >> 16;   // RNE truncate to bf16
    return (unsigned short)u;
}

__global__ __launch_bounds__(256, 2) void attn_part(
    const int*   __restrict__ zs,
    const float* __restrict__ ctx,
    const float* __restrict__ emb,
    float*       __restrict__ ws)
{
    __shared__ __align__(16) unsigned short s_emb [TZ   * SEMB_STRIDE];   // 17408 B
    __shared__ __align__(16) unsigned short s_embT[D_SZ * SEMBT_STRIDE];  // 18432 B
    __shared__ __align__(16) unsigned short s_P   [4 * WROWS * SP_STRIDE];// 9216 B

    const int tid  = threadIdx.x;
    const int wave = tid >> 6;
    const int lane = tid & 63;
    const int l15  = lane & 15;
    const int quad = lane >> 4;

    const int bg     = blockIdx.x;            // 0..15 batch group
    const int ch     = blockIdx.y;            // 0..31 z-chunk
    const int z_base = ch * CZ;
    const int wb0    = bg * TBLK + wave * WROWS;  // first batch row of this wave

    // ---- ctx A-fragments, scaled by 1/sqrt(D), held in registers whole kernel ----
    bf16x8 afrag[4];
    {
        const float scale = 0.08838834764831845f;  // 1/sqrt(128)
        const float* crow = ctx + (size_t)(wb0 + l15) * D_SZ;
#pragma unroll
        for (int ks = 0; ks < 4; ++ks) {
            const float* p = crow + ks * 32 + quad * 8;
            float4 x0 = *(const float4*)(p);
            float4 x1 = *(const float4*)(p + 4);
            bf16x8 a;
            a[0] = (short)f2bf(x0.x * scale); a[1] = (short)f2bf(x0.y * scale);
            a[2] = (short)f2bf(x0.z * scale); a[3] = (short)f2bf(x0.w * scale);
            a[4] = (short)f2bf(x1.x * scale); a[5] = (short)f2bf(x1.y * scale);
            a[6] = (short)f2bf(x1.z * scale); a[7] = (short)f2bf(x1.w * scale);
            afrag[ks] = a;
        }
    }

    // ---- online-softmax state (per reg-row r: row b = wb0 + quad*4 + r) ----
    float m_r[4], l_r[4];
    int   cnt_r[4];
    f32x4 acc2[8];
#pragma unroll
    for (int r = 0; r < 4; ++r) { m_r[r] = -1e30f; l_r[r] = 0.f; cnt_r[r] = 0; }
#pragma unroll
    for (int n = 0; n < 8; ++n) { acc2[n][0]=0.f; acc2[n][1]=0.f; acc2[n][2]=0.f; acc2[n][3]=0.f; }

    for (int it = 0; it < ITERS; ++it) {
        const int z0 = z_base + it * TZ;

        __syncthreads();   // previous tile's LDS reads complete

        // ---- stage row-major emb tile: thread (r=tid>>2, q3=tid&3) loads row r, d-range q3*32.. ----
        {
            const int r  = tid >> 2;
            const int q3 = tid & 3;
            const float* erow = emb + (size_t)(z0 + r) * D_SZ + q3 * 32;
            unsigned short* dst = s_emb + r * SEMB_STRIDE + q3 * 32;
#pragma unroll
            for (int u = 0; u < 8; ++u) {
                float4 x = *(const float4*)(erow + 4 * u);
                ushort4 h;
                h.x = f2bf(x.x); h.y = f2bf(x.y); h.z = f2bf(x.z); h.w = f2bf(x.w);
                *(ushort4*)(dst + 4 * u) = h;    // 8B-aligned
            }
        }
        // ---- stage transposed emb tile: thread (d=tid&127, zh=tid>>7) reads column d (coalesced
        //      across lanes: fixed z, lanes span d contiguously), writes a z-contiguous LDS row ----
        {
            const int d  = tid & 127;
            const int zh = tid >> 7;           // 0..1, 32 z each
            const float* ecol = emb + (size_t)(z0 + zh * 32) * D_SZ + d;
            unsigned short* dst = s_embT + d * SEMBT_STRIDE + zh * 32;
#pragma unroll
            for (int g = 0; g < 4; ++g) {       // groups of 8 z
                float v0 = ecol[(8*g + 0) * D_SZ]; float v1 = ecol[(8*g + 1) * D_SZ];
                float v2 = ecol[(8*g + 2) * D_SZ]; float v3 = ecol[(8*g + 3) * D_SZ];
                float v4 = ecol[(8*g + 4) * D_SZ]; float v5 = ecol[(8*g + 5) * D_SZ];
                float v6 = ecol[(8*g + 6) * D_SZ]; float v7 = ecol[(8*g + 7) * D_SZ];
                ushort2 h;
                h.x = f2bf(v0); h.y = f2bf(v1); *(ushort2*)(dst + 8*g + 0) = h;
                h.x = f2bf(v2); h.y = f2bf(v3); *(ushort2*)(dst + 8*g + 2) = h;
                h.x = f2bf(v4); h.y = f2bf(v5); *(ushort2*)(dst + 8*g + 4) = h;
                h.x = f2bf(v6); h.y = f2bf(v7); *(ushort2*)(dst + 8*g + 6) = h;
            }
        }

        // ---- mask bits: msk[nt][r] = z_sparse[b = wb0+quad*4+r][z0 + nt*16 + l15] > 0 ----
        int msk[4][4];
#pragma unroll
        for (int r = 0; r < 4; ++r) {
            const int b = wb0 + quad * 4 + r;
            const int* p = zs + (size_t)b * Z_SZ + z0 + l15;
#pragma unroll
            for (int nt = 0; nt < 4; ++nt) msk[nt][r] = (p[nt * 16] > 0) ? 1 : 0;
            cnt_r[r] += msk[0][r] + msk[1][r] + msk[2][r] + msk[3][r];
        }

        __syncthreads();   // staging visible

        // ---- GEMM1: S[16 x 64] = ctx_tile @ emb_tile^T (K = 128) ----
        f32x4 sfr[4];
#pragma unroll
        for (int nt = 0; nt < 4; ++nt) {
            f32x4 c; c[0]=0.f; c[1]=0.f; c[2]=0.f; c[3]=0.f;
            const unsigned short* bb = s_emb + (nt * 16 + l15) * SEMB_STRIDE + quad * 8;
#pragma unroll
            for (int ks = 0; ks < 4; ++ks) {
                bf16x8 bf = *(const bf16x8*)(bb + ks * 32);
                c = __builtin_amdgcn_mfma_f32_16x16x32_bf16(afrag[ks], bf, c, 0, 0, 0);
            }
            sfr[nt] = c;
        }

        // ---- masked online softmax (per-row stats, rows replicated across 16 lanes of a quad) ----
        float tmax[4];
#pragma unroll
        for (int r = 0; r < 4; ++r) {
            float a0 = msk[0][r] ? sfr[0][r] : -1e30f;
            float a1 = msk[1][r] ? sfr[1][r] : -1e30f;
            float a2 = msk[2][r] ? sfr[2][r] : -1e30f;
            float a3 = msk[3][r] ? sfr[3][r] : -1e30f;
            tmax[r] = fmaxf(fmaxf(a0, a1), fmaxf(a2, a3));
        }
#pragma unroll
        for (int s = 1; s < 16; s <<= 1) {
#pragma unroll
            for (int r = 0; r < 4; ++r) tmax[r] = fmaxf(tmax[r], __shfl_xor(tmax[r], s));
        }
        float alpha[4];
#pragma unroll
        for (int r = 0; r < 4; ++r) {
            float mnew = fmaxf(m_r[r], tmax[r]);
            alpha[r] = __expf(m_r[r] - mnew);    // m=-1e30 twice -> exp(0)=1, l stays 0
            m_r[r] = mnew;
            l_r[r] *= alpha[r];
        }
        // p = mask ? exp(s - m) : 0 ; write P to per-wave LDS (A-operand layout route)
        float psum[4]; psum[0]=0.f; psum[1]=0.f; psum[2]=0.f; psum[3]=0.f;
        unsigned short* pw = s_P + wave * (WROWS * SP_STRIDE);
#pragma unroll
        for (int nt = 0; nt < 4; ++nt) {
#pragma unroll
            for (int r = 0; r < 4; ++r) {
                float p = msk[nt][r] ? __expf(sfr[nt][r] - m_r[r]) : 0.f;
                psum[r] += p;
                pw[(quad * 4 + r) * SP_STRIDE + nt * 16 + l15] = f2bf(p);
            }
        }
#pragma unroll
        for (int s = 1; s < 16; s <<= 1) {
#pragma unroll
            for (int r = 0; r < 4; ++r) psum[r] += __shfl_xor(psum[r], s);
        }
#pragma unroll
        for (int r = 0; r < 4; ++r) l_r[r] += psum[r];

        // rescale O accumulator by alpha (alpha[r] replicated across quad lanes)
#pragma unroll
        for (int n = 0; n < 8; ++n) {
#pragma unroll
            for (int r = 0; r < 4; ++r) acc2[n][r] *= alpha[r];
        }

        // ---- GEMM2: O[16 x 128] += P[16 x 64] @ emb_tile[64 x 128] (K = 64) ----
        const unsigned short* pb = pw + l15 * SP_STRIDE + quad * 8;
        bf16x8 pA0 = *(const bf16x8*)(pb);
        bf16x8 pA1 = *(const bf16x8*)(pb + 32);
#pragma unroll
        for (int nt2 = 0; nt2 < 8; ++nt2) {
            const unsigned short* tb = s_embT + (nt2 * 16 + l15) * SEMBT_STRIDE + quad * 8;
            bf16x8 b0 = *(const bf16x8*)(tb);
            bf16x8 b1 = *(const bf16x8*)(tb + 32);
            acc2[nt2] = __builtin_amdgcn_mfma_f32_16x16x32_bf16(pA0, b0, acc2[nt2], 0, 0, 0);
            acc2[nt2] = __builtin_amdgcn_mfma_f32_16x16x32_bf16(pA1, b1, acc2[nt2], 0, 0, 0);
        }
    }

    // ---- epilogue: partial O, m, l, count to workspace ----
#pragma unroll
    for (int nt2 = 0; nt2 < 8; ++nt2) {
#pragma unroll
        for (int r = 0; r < 4; ++r) {
            const int b = wb0 + quad * 4 + r;
            ws[WS_O + ((size_t)ch * B_SZ + b) * D_SZ + nt2 * 16 + l15] = acc2[nt2][r];
        }
    }
    float cntf[4];
#pragma unroll
    for (int r = 0; r < 4; ++r) cntf[r] = (float)cnt_r[r];
#pragma unroll
    for (int s = 1; s < 16; s <<= 1) {
#pragma unroll
        for (int r = 0; r < 4; ++r) cntf[r] += __shfl_xor(cntf[r], s);
    }
    if (l15 == 0) {
#pragma unroll
        for (int r = 0; r < 4; ++r) {
            const int b = wb0 + quad * 4 + r;
            ws[WS_M + ch * B_SZ + b] = m_r[r];
            ws[WS_L + ch * B_SZ + b] = l_r[r];
            ws[WS_C + ch * B_SZ + b] = cntf[r];
        }
    }
}

__global__ __launch_bounds__(128) void attn_reduce(
    const float* __restrict__ ws, float* __restrict__ out)
{
    const int b = blockIdx.x;
    const int d = threadIdx.x;
    const float* mP = ws + WS_M;
    const float* lP = ws + WS_L;
    const float* cP = ws + WS_C;

    float M = -1e30f;
#pragma unroll
    for (int c = 0; c < NZ; ++c) M = fmaxf(M, mP[c * B_SZ + b]);

    float L = 0.f, C = 0.f, acc = 0.f;
#pragma unroll
    for (int c = 0; c < NZ; ++c) {
        float w = __expf(mP[c * B_SZ + b] - M);
        L += lP[c * B_SZ + b] * w;
        C += cP[c * B_SZ + b];
        acc += ws[WS_O + ((size_t)c * B_SZ + b) * D_SZ + d] * w;
    }
    float cnt = fmaxf(C, 1.0f);
    out[(size_t)b * D_SZ + d] = (L > 0.f) ? acc / (L * cnt) : 0.f;
}

extern "C" void kernel_launch(void* const* d_in, const int* in_sizes, int n_in,
                              void* d_out, int out_size, void* d_ws, size_t ws_size,
                              hipStream_t stream) {
    (void)in_sizes; (void)n_in; (void)out_size; (void)ws_size;
    const int*   zs  = (const int*)  d_in[0];
    const float* ctx = (const float*)d_in[1];
    const float* emb = (const float*)d_in[2];
    float* out = (float*)d_out;
    float* ws  = (float*)d_ws;

    dim3 grid1(B_SZ / TBLK, NZ);   // (16, 32): consecutive blocks share a z-chunk -> L2 reuse of emb
    attn_part<<<grid1, 256, 0, stream>>>(zs, ctx, emb, ws);
    attn_reduce<<<B_SZ, 128, 0, stream>>>(ws, out);
}